// Round 6
// baseline (239.035 us; speedup 1.0000x reference)
//
#include <hip/hip_runtime.h>
#include <hip/hip_bf16.h>
#include <hip/hip_fp16.h>
#include <cstddef>

// Problem constants
#define NB 2
#define QN 12240
#define SN 12240
#define MREAL 24480          // NB*QN rows
#define MPAD  24576          // 192 * 128
#define MT    192            // M tiles of 128

typedef unsigned short ushortT;
typedef unsigned int uintT;
typedef __bf16 bf16x8 __attribute__((ext_vector_type(8)));
typedef float f32x4 __attribute__((ext_vector_type(4)));

__device__ __forceinline__ ushortT f2bf(float f) {
    uintT u = __float_as_uint(f);
    uintT r = u + 0x7fffu + ((u >> 16) & 1u);   // RNE
    return (ushortT)(r >> 16);
}
__device__ __forceinline__ float bf_lo(uintT u) {   // low bf16 -> f32
    return __uint_as_float(u << 16);
}
__device__ __forceinline__ float bf_hi(uintT u) {   // high bf16 -> f32
    return __uint_as_float(u & 0xffff0000u);
}

// ---------------------------------------------------------------------------
// Merged cast kernel.
// bx in [0,3060): queries -> q_bf (bf16)
// bx in [3060,6120): src -> src_bf
// bx in [6120,7016): weight cast+transpose (W_val/W_attn/W_off/W_out)
// ---------------------------------------------------------------------------
__global__ __launch_bounds__(256) void cast_all(
    const float* __restrict__ q, const float* __restrict__ src,
    const float* __restrict__ Wval, const float* __restrict__ Wattn,
    const float* __restrict__ Woff, const float* __restrict__ Wout,
    ushortT* __restrict__ qb, ushortT* __restrict__ sb,
    ushortT* __restrict__ tval, ushortT* __restrict__ tlo,
    ushortT* __restrict__ tout)
{
    int bx = blockIdx.x;
    if (bx < 6120) {
        const int issrc = bx >= 3060;
        const size_t idx = ((size_t)(bx - (issrc ? 3060 : 0)) * 256 + threadIdx.x) * 8;
        const float* in = issrc ? src : q;
        ushortT* out = issrc ? sb : qb;
        const float4 a = *(const float4*)(in + idx);
        const float4 b = *(const float4*)(in + idx + 4);
        uint4 o;
        o.x = (uintT)f2bf(a.x) | ((uintT)f2bf(a.y) << 16);
        o.y = (uintT)f2bf(a.z) | ((uintT)f2bf(a.w) << 16);
        o.z = (uintT)f2bf(b.x) | ((uintT)f2bf(b.y) << 16);
        o.w = (uintT)f2bf(b.z) | ((uintT)f2bf(b.w) << 16);
        *(uint4*)(out + idx) = o;
        return;
    }
    bx -= 6120;
    const float* W; ushortT* T; int n, Nw, trow;
    if (bx < 256)      { W = Wval;  T = tval; n = bx;       Nw = 256; trow = n; }
    else if (bx < 384) { W = Wattn; T = tlo;  n = bx - 256; Nw = 128; trow = n; }
    else if (bx < 640) { W = Woff;  T = tlo;  n = bx - 384; Nw = 256; trow = n + 128; }
    else               { W = Wout;  T = tout; n = bx - 640; Nw = 256; trow = n; }
    const int k = threadIdx.x;
    T[(size_t)trow * 256 + k] = f2bf(W[(size_t)k * Nw + n]);
}

// ---------------------------------------------------------------------------
// No-LDS direct-from-cache MFMA GEMM core. 128x128 tile, 4 waves (2x2 of
// 64x64). Each lane loads its MFMA fragments straight from global (16B
// dwordx4, L2/L3-resident operands); no barriers, no LDS.
// ---------------------------------------------------------------------------
__device__ __forceinline__ void gemm_core_128(
    const ushortT* __restrict__ A, const ushortT* __restrict__ Bt,
    int row0, int col0, int lane, int wr, int wc, f32x4 acc[4][4])
{
    const int mrow = lane & 15;
    const int kq   = (lane >> 4) * 8;

    const ushortT* Ap = A  + (size_t)(row0 + wr + mrow) * 256 + kq;
    const ushortT* Bp = Bt + (size_t)(col0 + wc + mrow) * 256 + kq;

    #pragma unroll 2
    for (int k0 = 0; k0 < 256; k0 += 32) {
        bf16x8 af[4], bfr[4];
        #pragma unroll
        for (int i = 0; i < 4; i++)
            af[i] = *(const bf16x8*)(Ap + (size_t)i * 16 * 256 + k0);
        #pragma unroll
        for (int j = 0; j < 4; j++)
            bfr[j] = *(const bf16x8*)(Bp + (size_t)j * 16 * 256 + k0);
        #pragma unroll
        for (int i = 0; i < 4; i++)
            #pragma unroll
            for (int j = 0; j < 4; j++)
                acc[i][j] = __builtin_amdgcn_mfma_f32_16x16x32_bf16(
                    af[i], bfr[j], acc[i][j], 0, 0, 0);
    }
}

// ---------------------------------------------------------------------------
// Fused v + (logits|off) GEMM, flat grid (5 x-blocks).
// bx<2: v = src@W_val (col0=bx*128, bf16 out, Ntot=256)
// bx>=2: lo = q@[W_attn;W_off] (col0=(bx-2)*128, fp32 out, Ntot=384)
// ---------------------------------------------------------------------------
__global__ __launch_bounds__(256) void gemm_vlo(
    const ushortT* __restrict__ q_bf, const ushortT* __restrict__ src_bf,
    const ushortT* __restrict__ wt_val, const ushortT* __restrict__ wt_lo,
    const float* __restrict__ b_val, const float* __restrict__ b_attn,
    const float* __restrict__ b_off,
    ushortT* __restrict__ v_bf, float* __restrict__ lo_ws)
{
    const int z = blockIdx.x >= 2;
    const int col0 = (z ? blockIdx.x - 2 : blockIdx.x) * 128;
    const ushortT* A  = z ? q_bf : src_bf;
    const ushortT* Bt = z ? wt_lo : wt_val;

    const int tid  = threadIdx.x;
    const int wave = tid >> 6;
    const int lane = tid & 63;
    const int row0 = blockIdx.y * 128;
    const int wr = (wave >> 1) * 64;
    const int wc = (wave & 1) * 64;

    f32x4 acc[4][4];
    #pragma unroll
    for (int i = 0; i < 4; i++)
        #pragma unroll
        for (int j = 0; j < 4; j++)
            acc[i][j] = (f32x4)0.f;

    gemm_core_128(A, Bt, row0, col0, lane, wr, wc, acc);

    const float* bp = z ? ((col0 < 128) ? b_attn : b_off) : b_val;
    const int cofs  = (z && col0 >= 128) ? 128 : 0;

    #pragma unroll
    for (int i = 0; i < 4; i++) {
        const int rbase = row0 + wr + i * 16 + ((lane >> 4) << 2);
        #pragma unroll
        for (int j = 0; j < 4; j++) {
            const int col = col0 + wc + j * 16 + (lane & 15);
            const float bb = bp[col - cofs];
            #pragma unroll
            for (int r = 0; r < 4; r++) {
                const int row = rbase + r;
                if (row < MREAL) {
                    const float val = acc[i][j][r] + bb;
                    if (z) lo_ws[(size_t)row * 384 + col] = val;
                    else   v_bf[(size_t)row * 256 + col] = f2bf(val);
                }
            }
        }
    }
}

// ---------------------------------------------------------------------------
// Out GEMM: out(MREAL,256) = mdv(bf16) @ wt_out^T + b_out (fp32 to d_out).
// ---------------------------------------------------------------------------
__global__ __launch_bounds__(256) void gemm_out(
    const ushortT* __restrict__ A, const ushortT* __restrict__ Bt,
    const float* __restrict__ bias, float* __restrict__ C)
{
    const int tid  = threadIdx.x;
    const int wave = tid >> 6;
    const int lane = tid & 63;
    const int row0 = blockIdx.y * 128;
    const int col0 = blockIdx.x * 128;
    const int wr = (wave >> 1) * 64;
    const int wc = (wave & 1) * 64;

    f32x4 acc[4][4];
    #pragma unroll
    for (int i = 0; i < 4; i++)
        #pragma unroll
        for (int j = 0; j < 4; j++)
            acc[i][j] = (f32x4)0.f;

    gemm_core_128(A, Bt, row0, col0, lane, wr, wc, acc);

    #pragma unroll
    for (int i = 0; i < 4; i++) {
        const int rbase = row0 + wr + i * 16 + ((lane >> 4) << 2);
        #pragma unroll
        for (int j = 0; j < 4; j++) {
            const int col = col0 + wc + j * 16 + (lane & 15);
            const float bb = bias[col];
            #pragma unroll
            for (int r = 0; r < 4; r++) {
                const int row = rbase + r;
                if (row < MREAL)
                    C[(size_t)row * 256 + col] = acc[i][j][r] + bb;
            }
        }
    }
}

// ---------------------------------------------------------------------------
// Two-phase sample kernel, wave-owns-query. Block = 4 waves = 4 queries.
// Phase 1 (lane=(m,p)): softmax via shfl over 8 p-lanes; per point emit ONE
//   16B record {base_byte_off, dx|dyrow<<16, half2 w01, half2 w23}.
// Phase 2 (lane=(m,c)): per point 1x ds_read_b128, 4x 8B gathers, FMAs.
// ---------------------------------------------------------------------------
__global__ __launch_bounds__(256) void sample_kernel(
    const float* __restrict__ lo,       // (N*Q, 384): [0,128) logits, [128,384) off
    const float* __restrict__ geom,     // (N*Q, 4)
    const ushortT* __restrict__ v,      // (N*S, 256) bf16
    ushortT* __restrict__ out)          // (N*Q, 256) bf16 mdv
{
    const int tid  = threadIdx.x;
    const int w    = tid >> 6;          // wave = query offset
    const int lane = tid & 63;
    const int m    = lane >> 3;         // head, same in both phases
    const int n    = blockIdx.y;
    const int q0   = blockIdx.x << 2;

    __shared__ __attribute__((aligned(16))) int pls[4][544];   // 8704 B

    const size_t qb = (size_t)n * QN + q0 + w;

    // ---- phase 1 ----
    {
        const int p = lane & 7;                  // point pair 0..7
        const float* lorow = lo + qb * 384;
        const float2 lg = *(const float2*)(lorow + m * 16 + p * 2);
        const float4 of = *(const float4*)(lorow + 128 + m * 32 + p * 4);
        const float4 g  = *(const float4*)(geom + qb * 4);

        float mx = fmaxf(lg.x, lg.y);
        mx = fmaxf(mx, __shfl_xor(mx, 1));
        mx = fmaxf(mx, __shfl_xor(mx, 2));
        mx = fmaxf(mx, __shfl_xor(mx, 4));
        const float e0 = __expf(lg.x - mx);
        const float e1 = __expf(lg.y - mx);
        float s = e0 + e1;
        s += __shfl_xor(s, 1);
        s += __shfl_xor(s, 2);
        s += __shfl_xor(s, 4);
        const float inv = 1.f / s;

        const int l  = p >> 1;
        const int Wl = 96 >> l;
        const int s0 = (l == 0) ? 0 : (l == 1) ? 9216 : (l == 2) ? 11520 : 12096;
        const float cx = g.x, cy = g.y;
        const float sx = g.z * 0.125f, sy = g.w * 0.125f;
        int* myrec = &pls[w][m * 68 + p * 8];

        #pragma unroll
        for (int t = 0; t < 2; t++) {
            const float ox = t ? of.z : of.x;
            const float oy = t ? of.w : of.y;
            const float wa = (t ? e1 : e0) * inv;

            const float x = (cx + ox * sx) * (float)Wl - 0.5f;
            const float y = (cy + oy * sy) * (float)Wl - 0.5f;
            const float xf = floorf(x), yf = floorf(y);
            const int x0 = (int)xf, y0 = (int)yf;
            const float wx = x - xf, wy = y - yf;

            const bool vx0 = (x0 >= 0) & (x0 < Wl);
            const bool vx1 = (x0 + 1 >= 0) & (x0 + 1 < Wl);
            const bool vy0 = (y0 >= 0) & (y0 < Wl);
            const bool vy1 = (y0 + 1 >= 0) & (y0 + 1 < Wl);

            const float w00 = (vx0 & vy0) ? wa * (1.f - wx) * (1.f - wy) : 0.f;
            const float w10 = (vx1 & vy0) ? wa * wx * (1.f - wy) : 0.f;
            const float w01 = (vx0 & vy1) ? wa * (1.f - wx) * wy : 0.f;
            const float w11 = (vx1 & vy1) ? wa * wx * wy : 0.f;

            const int xc0 = min(max(x0, 0), Wl - 1);
            const int xc1 = min(max(x0 + 1, 0), Wl - 1);
            const int yc0 = min(max(y0, 0), Wl - 1);
            const int yc1 = min(max(y0 + 1, 0), Wl - 1);

            const int iv0   = (s0 + yc0 * Wl + xc0) << 9;   // byte offset, row 512B
            const int dx    = (xc1 - xc0) << 9;             // 0 or 512
            const int dyrow = ((yc1 - yc0) * Wl) << 9;      // 0..49152
            __half2 h01 = __floats2half2_rn(w00, w10);
            __half2 h23 = __floats2half2_rn(w01, w11);
            int4 rec;
            rec.x = iv0;
            rec.y = dx | (dyrow << 16);
            rec.z = *reinterpret_cast<int*>(&h01);
            rec.w = *reinterpret_cast<int*>(&h23);
            *(int4*)(myrec + t * 4) = rec;
        }
    }
    __syncthreads();

    // ---- phase 2 ----
    const int c = lane & 7;
    const int chan_byte = (m * 32 + c * 4) * 2;
    const unsigned char* vb =
        (const unsigned char*)(v + (size_t)n * SN * 256);
    const int* grec = &pls[w][m * 68];

    float a0 = 0.f, a1 = 0.f, a2 = 0.f, a3 = 0.f;

    #pragma unroll
    for (int lk = 0; lk < 16; lk++) {
        const int4 rec = *(const int4*)(grec + lk * 4);
        const int base = rec.x + chan_byte;
        const int dx   = rec.y & 0xffff;
        const int dy   = ((uintT)rec.y) >> 16;

        const uint2 u0 = *(const uint2*)(vb + base);
        const uint2 u1 = *(const uint2*)(vb + base + dx);
        const uint2 u2 = *(const uint2*)(vb + base + dy);
        const uint2 u3 = *(const uint2*)(vb + base + dy + dx);

        const __half2 h01 = *reinterpret_cast<const __half2*>(&rec.z);
        const __half2 h23 = *reinterpret_cast<const __half2*>(&rec.w);
        const float2 wlo = __half22float2(h01);
        const float2 whi = __half22float2(h23);

        a0 += wlo.x * bf_lo(u0.x) + wlo.y * bf_lo(u1.x) + whi.x * bf_lo(u2.x) + whi.y * bf_lo(u3.x);
        a1 += wlo.x * bf_hi(u0.x) + wlo.y * bf_hi(u1.x) + whi.x * bf_hi(u2.x) + whi.y * bf_hi(u3.x);
        a2 += wlo.x * bf_lo(u0.y) + wlo.y * bf_lo(u1.y) + whi.x * bf_lo(u2.y) + whi.y * bf_lo(u3.y);
        a3 += wlo.x * bf_hi(u0.y) + wlo.y * bf_hi(u1.y) + whi.x * bf_hi(u2.y) + whi.y * bf_hi(u3.y);
    }

    ushort4 o;
    o.x = f2bf(a0); o.y = f2bf(a1); o.z = f2bf(a2); o.w = f2bf(a3);
    *(ushort4*)(out + qb * 256 + m * 32 + c * 4) = o;
}

// ---------------------------------------------------------------------------
extern "C" void kernel_launch(void* const* d_in, const int* in_sizes, int n_in,
                              void* d_out, int out_size, void* d_ws, size_t ws_size,
                              hipStream_t stream)
{
    const float* queries = (const float*)d_in[0];
    const float* geom    = (const float*)d_in[1];
    const float* src     = (const float*)d_in[2];
    const float* W_off   = (const float*)d_in[3];
    const float* b_off   = (const float*)d_in[4];
    const float* W_attn  = (const float*)d_in[5];
    const float* b_attn  = (const float*)d_in[6];
    const float* W_val   = (const float*)d_in[7];
    const float* b_val   = (const float*)d_in[8];
    const float* W_out   = (const float*)d_in[9];
    const float* b_out   = (const float*)d_in[10];
    float* out = (float*)d_out;

    ushortT* wsb = (ushortT*)d_ws;
    const size_t PADROW = (size_t)MPAD * 256;          // 6,291,456 elems
    ushortT* q_bf    = wsb;
    ushortT* srcmdv  = wsb + PADROW;                   // src_bf, later mdv_bf
    ushortT* v_bf    = wsb + 2 * PADROW;
    ushortT* wt_val  = wsb + 3 * PADROW;               // 256*256
    ushortT* wt_lo   = wt_val + 65536;                 // 384*256
    ushortT* wt_out  = wt_lo + 98304;                  // 256*256
    float* lo_ws = (float*)(wt_out + 65536);           // 24480*384 fp32
    // total ~75.8 MB

    dim3 blk(256);

    cast_all<<<dim3(7016), blk, 0, stream>>>(
        queries, src, W_val, W_attn, W_off, W_out,
        q_bf, srcmdv, wt_val, wt_lo, wt_out);

    // bx<2: v = src@W_val -> v_bf (bf16); bx>=2: lo = q@[W_attn;W_off] -> lo_ws
    gemm_vlo<<<dim3(5, MT), blk, 0, stream>>>(
        q_bf, srcmdv, wt_val, wt_lo, b_val, b_attn, b_off, v_bf, lo_ws);

    sample_kernel<<<dim3(QN / 4, NB), blk, 0, stream>>>(
        lo_ws, geom, v_bf, srcmdv);

    gemm_out<<<dim3(2, MT), blk, 0, stream>>>(srcmdv, wt_out, b_out, out);
}

// Round 7
// 206.483 us; speedup vs baseline: 1.1577x; 1.1577x over previous
//
#include <hip/hip_runtime.h>
#include <hip/hip_bf16.h>
#include <hip/hip_fp16.h>
#include <cstddef>

// Problem constants
#define NB 2
#define QN 12240
#define SN 12240
#define MREAL 24480          // NB*QN rows
#define MPAD  24576          // 192 * 128
#define MT    192            // M tiles of 128

typedef unsigned short ushortT;
typedef unsigned int uintT;
typedef __bf16 bf16x8 __attribute__((ext_vector_type(8)));
typedef float f32x4 __attribute__((ext_vector_type(4)));

__device__ __forceinline__ ushortT f2bf(float f) {
    uintT u = __float_as_uint(f);
    uintT r = u + 0x7fffu + ((u >> 16) & 1u);   // RNE
    return (ushortT)(r >> 16);
}
__device__ __forceinline__ float bf_lo(uintT u) {   // low bf16 -> f32
    return __uint_as_float(u << 16);
}
__device__ __forceinline__ float bf_hi(uintT u) {   // high bf16 -> f32
    return __uint_as_float(u & 0xffff0000u);
}

__device__ __forceinline__ void async_ld16(const ushortT* g, ushortT* l) {
    __builtin_amdgcn_global_load_lds(
        (const __attribute__((address_space(1))) unsigned int*)g,
        (__attribute__((address_space(3))) unsigned int*)l, 16, 0, 0);
}

// ---------------------------------------------------------------------------
// Merged cast kernel.
// bx in [0,3060): queries -> q_bf (bf16)
// bx in [3060,6120): src -> src_bf
// bx in [6120,7016): weight cast+transpose (W_val/W_attn/W_off/W_out)
// ---------------------------------------------------------------------------
__global__ __launch_bounds__(256) void cast_all(
    const float* __restrict__ q, const float* __restrict__ src,
    const float* __restrict__ Wval, const float* __restrict__ Wattn,
    const float* __restrict__ Woff, const float* __restrict__ Wout,
    ushortT* __restrict__ qb, ushortT* __restrict__ sb,
    ushortT* __restrict__ tval, ushortT* __restrict__ tlo,
    ushortT* __restrict__ tout)
{
    int bx = blockIdx.x;
    if (bx < 6120) {
        const int issrc = bx >= 3060;
        const size_t idx = ((size_t)(bx - (issrc ? 3060 : 0)) * 256 + threadIdx.x) * 8;
        const float* in = issrc ? src : q;
        ushortT* out = issrc ? sb : qb;
        const float4 a = *(const float4*)(in + idx);
        const float4 b = *(const float4*)(in + idx + 4);
        uint4 o;
        o.x = (uintT)f2bf(a.x) | ((uintT)f2bf(a.y) << 16);
        o.y = (uintT)f2bf(a.z) | ((uintT)f2bf(a.w) << 16);
        o.z = (uintT)f2bf(b.x) | ((uintT)f2bf(b.y) << 16);
        o.w = (uintT)f2bf(b.z) | ((uintT)f2bf(b.w) << 16);
        *(uint4*)(out + idx) = o;
        return;
    }
    bx -= 6120;
    const float* W; ushortT* T; int n, Nw, trow;
    if (bx < 256)      { W = Wval;  T = tval; n = bx;       Nw = 256; trow = n; }
    else if (bx < 384) { W = Wattn; T = tlo;  n = bx - 256; Nw = 128; trow = n; }
    else if (bx < 640) { W = Woff;  T = tlo;  n = bx - 384; Nw = 256; trow = n + 128; }
    else               { W = Wout;  T = tout; n = bx - 640; Nw = 256; trow = n; }
    const int k = threadIdx.x;
    T[(size_t)trow * 256 + k] = f2bf(W[(size_t)k * Nw + n]);
}

// ---------------------------------------------------------------------------
// Fused v + (logits|off) GEMM, LDS-staged (R5 structure), flat grid.
// bx<2: v = src@W_val -> v_bf in HEAD-MAJOR layout (n, head, s, 32ch) bf16
// bx>=2: lo = q@[W_attn;W_off] (col0=(bx-2)*128, fp32 out, Ntot=384)
// ---------------------------------------------------------------------------
__global__ __launch_bounds__(256) void gemm_vlo(
    const ushortT* __restrict__ q_bf, const ushortT* __restrict__ src_bf,
    const ushortT* __restrict__ wt_val, const ushortT* __restrict__ wt_lo,
    const float* __restrict__ b_val, const float* __restrict__ b_attn,
    const float* __restrict__ b_off,
    ushortT* __restrict__ v_bf, float* __restrict__ lo_ws)
{
    const int z = blockIdx.x >= 2;
    const int col0 = (z ? blockIdx.x - 2 : blockIdx.x) * 128;

    __shared__ __attribute__((aligned(16))) ushortT As[128 * 32];
    __shared__ __attribute__((aligned(16))) ushortT Bs[128 * 32];

    const ushortT* A  = z ? q_bf : src_bf;
    const ushortT* Bt = z ? wt_lo : wt_val;

    const int tid  = threadIdx.x;
    const int wave = tid >> 6;
    const int lane = tid & 63;
    const int row0 = blockIdx.y * 128;
    const int wr = (wave >> 1) * 64;
    const int wc = (wave & 1) * 64;

    f32x4 acc[4][4];
    #pragma unroll
    for (int i = 0; i < 4; i++)
        #pragma unroll
        for (int j = 0; j < 4; j++)
            acc[i][j] = (f32x4)0.f;

    const int srow = (lane >> 2);
    const int sk8  = (lane & 3) * 8;

    for (int k0 = 0; k0 < 256; k0 += 32) {
        #pragma unroll
        for (int j = 0; j < 2; j++) {
            const int r = wave * 32 + j * 16;
            async_ld16(A  + (size_t)(row0 + r + srow) * 256 + k0 + sk8, &As[r * 32]);
            async_ld16(Bt + (size_t)(col0 + r + srow) * 256 + k0 + sk8, &Bs[r * 32]);
        }
        __syncthreads();

        bf16x8 af[4], bfr[4];
        const int mrow = lane & 15;
        const int kq   = (lane >> 4) * 8;
        #pragma unroll
        for (int i = 0; i < 4; i++) {
            af[i]  = *(const bf16x8*)&As[(wr + i * 16 + mrow) * 32 + kq];
            bfr[i] = *(const bf16x8*)&Bs[(wc + i * 16 + mrow) * 32 + kq];
        }
        #pragma unroll
        for (int i = 0; i < 4; i++)
            #pragma unroll
            for (int j = 0; j < 4; j++)
                acc[i][j] = __builtin_amdgcn_mfma_f32_16x16x32_bf16(
                    af[i], bfr[j], acc[i][j], 0, 0, 0);
        __syncthreads();
    }

    const float* bp = z ? ((col0 < 128) ? b_attn : b_off) : b_val;
    const int cofs  = (z && col0 >= 128) ? 128 : 0;

    #pragma unroll
    for (int i = 0; i < 4; i++) {
        const int rbase = row0 + wr + i * 16 + ((lane >> 4) << 2);
        #pragma unroll
        for (int j = 0; j < 4; j++) {
            const int col = col0 + wc + j * 16 + (lane & 15);
            const float bb = bp[col - cofs];
            #pragma unroll
            for (int r = 0; r < 4; r++) {
                const int row = rbase + r;
                if (row < MREAL) {
                    const float val = acc[i][j][r] + bb;
                    if (z) {
                        lo_ws[(size_t)row * 384 + col] = val;
                    } else {
                        // head-major v: (n, head, s, ch)
                        const int nn = row / SN;
                        const int s  = row - nn * SN;
                        const int head = col >> 5, ch = col & 31;
                        v_bf[(((size_t)nn * 8 + head) * SN + s) * 32 + ch] = f2bf(val);
                    }
                }
            }
        }
    }
}

// ---------------------------------------------------------------------------
// Out GEMM (R5 LDS structure): out = mdv(bf16) @ wt_out^T + b_out (fp32).
// ---------------------------------------------------------------------------
__global__ __launch_bounds__(256) void gemm_out(
    const ushortT* __restrict__ A, const ushortT* __restrict__ Bt,
    const float* __restrict__ bias, float* __restrict__ C)
{
    __shared__ __attribute__((aligned(16))) ushortT As[128 * 32];
    __shared__ __attribute__((aligned(16))) ushortT Bs[128 * 32];

    const int tid  = threadIdx.x;
    const int wave = tid >> 6;
    const int lane = tid & 63;
    const int row0 = blockIdx.y * 128;
    const int col0 = blockIdx.x * 128;
    const int wr = (wave >> 1) * 64;
    const int wc = (wave & 1) * 64;

    f32x4 acc[4][4];
    #pragma unroll
    for (int i = 0; i < 4; i++)
        #pragma unroll
        for (int j = 0; j < 4; j++)
            acc[i][j] = (f32x4)0.f;

    const int srow = (lane >> 2);
    const int sk8  = (lane & 3) * 8;

    for (int k0 = 0; k0 < 256; k0 += 32) {
        #pragma unroll
        for (int j = 0; j < 2; j++) {
            const int r = wave * 32 + j * 16;
            async_ld16(A  + (size_t)(row0 + r + srow) * 256 + k0 + sk8, &As[r * 32]);
            async_ld16(Bt + (size_t)(col0 + r + srow) * 256 + k0 + sk8, &Bs[r * 32]);
        }
        __syncthreads();

        bf16x8 af[4], bfr[4];
        const int mrow = lane & 15;
        const int kq   = (lane >> 4) * 8;
        #pragma unroll
        for (int i = 0; i < 4; i++) {
            af[i]  = *(const bf16x8*)&As[(wr + i * 16 + mrow) * 32 + kq];
            bfr[i] = *(const bf16x8*)&Bs[(wc + i * 16 + mrow) * 32 + kq];
        }
        #pragma unroll
        for (int i = 0; i < 4; i++)
            #pragma unroll
            for (int j = 0; j < 4; j++)
                acc[i][j] = __builtin_amdgcn_mfma_f32_16x16x32_bf16(
                    af[i], bfr[j], acc[i][j], 0, 0, 0);
        __syncthreads();
    }

    #pragma unroll
    for (int i = 0; i < 4; i++) {
        const int rbase = row0 + wr + i * 16 + ((lane >> 4) << 2);
        #pragma unroll
        for (int j = 0; j < 4; j++) {
            const int col = col0 + wc + j * 16 + (lane & 15);
            const float bb = bias[col];
            #pragma unroll
            for (int r = 0; r < 4; r++) {
                const int row = rbase + r;
                if (row < MREAL)
                    C[(size_t)row * 256 + col] = acc[i][j][r] + bb;
            }
        }
    }
}

// ---------------------------------------------------------------------------
// Per-head two-phase sample kernel. Block = 128 threads = 2 waves =
// 16 queries of ONE head (grid: 765 x 8 heads x 2 batch). The v gather
// working set per head-plane is 0.78 MB (fits XCD L2); co-resident blocks
// share a head (head = blockIdx.y, slow dim) -> gathers are L2 hits.
// Phase 1 (lane=(qi,p)): softmax via shfl over 8 p-lanes; per point ONE
//   16B LDS record {base_byte_off, dx|dyrow<<16, half2 w01, half2 w23}.
// Phase 2 (lane=(qi,c)): per point 1x ds_read_b128 (broadcast over c,
//   conflict-free over qi), 4x 8B gathers in the head plane, FMAs.
// ---------------------------------------------------------------------------
__global__ __launch_bounds__(128) void sample_kernel(
    const float* __restrict__ lo,       // (N*Q, 384): [0,128) logits, [128,384) off
    const float* __restrict__ geom,     // (N*Q, 4)
    const ushortT* __restrict__ v,      // (N, 8, S, 32) bf16 head-major
    ushortT* __restrict__ out)          // (N*Q, 256) bf16 mdv
{
    const int tid  = threadIdx.x;
    const int w    = tid >> 6;          // wave 0/1
    const int lane = tid & 63;
    const int qi   = lane >> 3;         // query within wave's 8
    const int m    = blockIdx.y;        // head
    const int n    = blockIdx.z;
    const int q    = blockIdx.x * 16 + w * 8 + qi;

    __shared__ __attribute__((aligned(16))) int pls[2][544];   // 4352 B

    const size_t qb = (size_t)n * QN + q;

    // ---- phase 1 ----
    {
        const int p = lane & 7;                  // point pair 0..7
        const float* lorow = lo + qb * 384;
        const float2 lg = *(const float2*)(lorow + m * 16 + p * 2);
        const float4 of = *(const float4*)(lorow + 128 + m * 32 + p * 4);
        const float4 g  = *(const float4*)(geom + qb * 4);

        float mx = fmaxf(lg.x, lg.y);
        mx = fmaxf(mx, __shfl_xor(mx, 1));
        mx = fmaxf(mx, __shfl_xor(mx, 2));
        mx = fmaxf(mx, __shfl_xor(mx, 4));
        const float e0 = __expf(lg.x - mx);
        const float e1 = __expf(lg.y - mx);
        float s = e0 + e1;
        s += __shfl_xor(s, 1);
        s += __shfl_xor(s, 2);
        s += __shfl_xor(s, 4);
        const float inv = 1.f / s;

        const int l  = p >> 1;
        const int Wl = 96 >> l;
        const int s0 = (l == 0) ? 0 : (l == 1) ? 9216 : (l == 2) ? 11520 : 12096;
        const float cx = g.x, cy = g.y;
        const float sx = g.z * 0.125f, sy = g.w * 0.125f;
        int* myrec = &pls[w][qi * 68 + p * 8];

        #pragma unroll
        for (int t = 0; t < 2; t++) {
            const float ox = t ? of.z : of.x;
            const float oy = t ? of.w : of.y;
            const float wa = (t ? e1 : e0) * inv;

            const float x = (cx + ox * sx) * (float)Wl - 0.5f;
            const float y = (cy + oy * sy) * (float)Wl - 0.5f;
            const float xf = floorf(x), yf = floorf(y);
            const int x0 = (int)xf, y0 = (int)yf;
            const float wx = x - xf, wy = y - yf;

            const bool vx0 = (x0 >= 0) & (x0 < Wl);
            const bool vx1 = (x0 + 1 >= 0) & (x0 + 1 < Wl);
            const bool vy0 = (y0 >= 0) & (y0 < Wl);
            const bool vy1 = (y0 + 1 >= 0) & (y0 + 1 < Wl);

            const float w00 = (vx0 & vy0) ? wa * (1.f - wx) * (1.f - wy) : 0.f;
            const float w10 = (vx1 & vy0) ? wa * wx * (1.f - wy) : 0.f;
            const float w01 = (vx0 & vy1) ? wa * (1.f - wx) * wy : 0.f;
            const float w11 = (vx1 & vy1) ? wa * wx * wy : 0.f;

            const int xc0 = min(max(x0, 0), Wl - 1);
            const int xc1 = min(max(x0 + 1, 0), Wl - 1);
            const int yc0 = min(max(y0, 0), Wl - 1);
            const int yc1 = min(max(y0 + 1, 0), Wl - 1);

            const int iv0   = (s0 + yc0 * Wl + xc0) << 6;   // byte off, row 64B
            const int dx    = (xc1 - xc0) << 6;             // 0 or 64
            const int dyrow = ((yc1 - yc0) * Wl) << 6;      // 0..6144
            __half2 h01 = __floats2half2_rn(w00, w10);
            __half2 h23 = __floats2half2_rn(w01, w11);
            int4 rec;
            rec.x = iv0;
            rec.y = dx | (dyrow << 16);
            rec.z = *reinterpret_cast<int*>(&h01);
            rec.w = *reinterpret_cast<int*>(&h23);
            *(int4*)(myrec + t * 4) = rec;
        }
    }
    __syncthreads();

    // ---- phase 2 ----
    const int c = lane & 7;             // channel quad within head
    const unsigned char* vb = (const unsigned char*)
        (v + ((size_t)(n * 8 + m) * SN) * 32) + c * 8;
    const int* grec = &pls[w][qi * 68];

    float a0 = 0.f, a1 = 0.f, a2 = 0.f, a3 = 0.f;

    #pragma unroll
    for (int lk = 0; lk < 16; lk++) {
        const int4 rec = *(const int4*)(grec + lk * 4);
        const int base = rec.x;
        const int dx   = rec.y & 0xffff;
        const int dy   = ((uintT)rec.y) >> 16;

        const uint2 u0 = *(const uint2*)(vb + base);
        const uint2 u1 = *(const uint2*)(vb + base + dx);
        const uint2 u2 = *(const uint2*)(vb + base + dy);
        const uint2 u3 = *(const uint2*)(vb + base + dy + dx);

        const __half2 h01 = *reinterpret_cast<const __half2*>(&rec.z);
        const __half2 h23 = *reinterpret_cast<const __half2*>(&rec.w);
        const float2 wlo = __half22float2(h01);
        const float2 whi = __half22float2(h23);

        a0 += wlo.x * bf_lo(u0.x) + wlo.y * bf_lo(u1.x) + whi.x * bf_lo(u2.x) + whi.y * bf_lo(u3.x);
        a1 += wlo.x * bf_hi(u0.x) + wlo.y * bf_hi(u1.x) + whi.x * bf_hi(u2.x) + whi.y * bf_hi(u3.x);
        a2 += wlo.x * bf_lo(u0.y) + wlo.y * bf_lo(u1.y) + whi.x * bf_lo(u2.y) + whi.y * bf_lo(u3.y);
        a3 += wlo.x * bf_hi(u0.y) + wlo.y * bf_hi(u1.y) + whi.x * bf_hi(u2.y) + whi.y * bf_hi(u3.y);
    }

    ushort4 o;
    o.x = f2bf(a0); o.y = f2bf(a1); o.z = f2bf(a2); o.w = f2bf(a3);
    *(ushort4*)(out + qb * 256 + m * 32 + c * 4) = o;
}

// ---------------------------------------------------------------------------
extern "C" void kernel_launch(void* const* d_in, const int* in_sizes, int n_in,
                              void* d_out, int out_size, void* d_ws, size_t ws_size,
                              hipStream_t stream)
{
    const float* queries = (const float*)d_in[0];
    const float* geom    = (const float*)d_in[1];
    const float* src     = (const float*)d_in[2];
    const float* W_off   = (const float*)d_in[3];
    const float* b_off   = (const float*)d_in[4];
    const float* W_attn  = (const float*)d_in[5];
    const float* b_attn  = (const float*)d_in[6];
    const float* W_val   = (const float*)d_in[7];
    const float* b_val   = (const float*)d_in[8];
    const float* W_out   = (const float*)d_in[9];
    const float* b_out   = (const float*)d_in[10];
    float* out = (float*)d_out;

    ushortT* wsb = (ushortT*)d_ws;
    const size_t PADROW = (size_t)MPAD * 256;          // 6,291,456 elems
    ushortT* q_bf    = wsb;
    ushortT* srcmdv  = wsb + PADROW;                   // src_bf, later mdv_bf
    ushortT* v_bf    = wsb + 2 * PADROW;               // head-major v
    ushortT* wt_val  = wsb + 3 * PADROW;               // 256*256
    ushortT* wt_lo   = wt_val + 65536;                 // 384*256
    ushortT* wt_out  = wt_lo + 98304;                  // 256*256
    float* lo_ws = (float*)(wt_out + 65536);           // 24480*384 fp32
    // total ~75.8 MB

    dim3 blk(256);

    cast_all<<<dim3(7016), blk, 0, stream>>>(
        queries, src, W_val, W_attn, W_off, W_out,
        q_bf, srcmdv, wt_val, wt_lo, wt_out);

    // bx<2: v = src@W_val -> v_bf (bf16 head-major); bx>=2: lo -> lo_ws
    gemm_vlo<<<dim3(5, MT), blk, 0, stream>>>(
        q_bf, srcmdv, wt_val, wt_lo, b_val, b_attn, b_off, v_bf, lo_ws);

    sample_kernel<<<dim3(QN / 16, 8, NB), dim3(128), 0, stream>>>(
        lo_ws, geom, v_bf, srcmdv);

    gemm_out<<<dim3(2, MT), blk, 0, stream>>>(srcmdv, wt_out, b_out, out);
}